// Round 1
// baseline (800.727 us; speedup 1.0000x reference)
//
#include <hip/hip_runtime.h>
#include <hip/hip_bf16.h>
#include <stdint.h>

// ---------------------------------------------------------------------------
// GNNEncoder: 3 x (GCNConv -> BatchNorm1d(train) -> ELU)
// N=50000 nodes, E=1.6M edges, dims 128->128->128->64
//
// Pipeline per call:
//   CSR build (count -> scan -> scatter, coef precomputed)
//   per layer: GEMM (f32, BN+ELU of prev layer fused into load, bf16 h out)
//              AGG  (wave-per-node, f32 accum of bf16 msgs, writes pre-BN y)
//              COLSUM (BN batch stats) + FINALIZE (fold into scale/shift)
//   final: elementwise BN+ELU -> d_out
// ---------------------------------------------------------------------------

static __device__ __forceinline__ float bflo(uint32_t u) {
    union { uint32_t u; float f; } x; x.u = u << 16; return x.f;
}
static __device__ __forceinline__ float bfhi(uint32_t u) {
    union { uint32_t u; float f; } x; x.u = u & 0xffff0000u; return x.f;
}
static __device__ __forceinline__ uint16_t f2bf(float f) {
    union { float f; uint32_t u; } x; x.f = f;
    uint32_t r = x.u + 0x7fffu + ((x.u >> 16) & 1u);   // RNE
    return (uint16_t)(r >> 16);
}
static __device__ __forceinline__ float eluf(float v) {
    return v > 0.f ? v : expm1f(v);
}

// ---------------------------------------------------------------- CSR build
__global__ __launch_bounds__(256) void count_kernel(const int* __restrict__ dst,
                                                    int* __restrict__ deg, int E) {
    int e = blockIdx.x * 256 + threadIdx.x;
    if (e < E) atomicAdd(&deg[dst[e]], 1);
}

__global__ __launch_bounds__(256) void dis_kernel(const int* __restrict__ deg,
                                                  float* __restrict__ dis, int n) {
    int i = blockIdx.x * 256 + threadIdx.x;
    if (i < n) dis[i] = rsqrtf(1.0f + (float)deg[i]);
}

__global__ __launch_bounds__(1024) void scan_kernel(const int* __restrict__ deg,
                                                    int* __restrict__ row_start, int n) {
    __shared__ int wtot[16];
    int t = threadIdx.x, lane = t & 63, w = t >> 6;
    int carry = 0;
    for (int base = 0; base < n; base += 1024) {
        int i = base + t;
        int v = (i < n) ? deg[i] : 0;
        int x = v;
        #pragma unroll
        for (int off = 1; off < 64; off <<= 1) {
            int m = __shfl_up(x, off);
            if (lane >= off) x += m;
        }
        if (lane == 63) wtot[w] = x;
        __syncthreads();
        int woff = 0, tot = 0;
        #pragma unroll
        for (int j = 0; j < 16; ++j) {
            int wv = wtot[j];
            tot += wv;
            if (j < w) woff += wv;
        }
        if (i < n) row_start[i] = carry + woff + (x - v);  // exclusive
        carry += tot;
        __syncthreads();
    }
    if (t == 0) row_start[n] = carry;
}

__global__ __launch_bounds__(256) void scatter_kernel(
    const int* __restrict__ src, const int* __restrict__ dst,
    const int* __restrict__ row_start, int* __restrict__ cursor,
    const float* __restrict__ dis,
    int* __restrict__ csr_src, float* __restrict__ csr_coef, int E) {
    int e = blockIdx.x * 256 + threadIdx.x;
    if (e >= E) return;
    int d = dst[e], s = src[e];
    int pos = row_start[d] + atomicAdd(&cursor[d], 1);
    csr_src[pos] = s;
    csr_coef[pos] = dis[s] * dis[d];
}

// ------------------------------------------------------------------- GEMM
// h[n][F] (bf16) = act(in)[n][128] @ W[128][F];  act = BN+ELU (fused) or id.
// block: 512 threads, tile 128 rows x F cols, K=128 staged in LDS.
template <int F, bool BN>
__global__ __launch_bounds__(512) void gemm_kernel(
    const float* __restrict__ in, const float* __restrict__ W,
    const float* __restrict__ sc, const float* __restrict__ sh,
    uint16_t* __restrict__ h, int n) {
    constexpr int K = 128;
    constexpr int BM = 128;
    __shared__ float xs[K][BM + 4];   // transposed: xs[k][r]
    __shared__ float ws[K][F];
    int t = threadIdx.x;
    int row0 = blockIdx.x * BM;

    // load W (f32, coalesced float4)
    for (int i = t * 4; i < K * F; i += 512 * 4) {
        *(float4*)((float*)ws + i) = *(const float4*)(W + i);
    }
    // load + transform x tile, store transposed
    for (int idx = t; idx < BM * K / 4; idx += 512) {
        int r = idx >> 5;            // 32 float4 per row
        int k = (idx & 31) << 2;
        int gr = row0 + r;
        float4 v = make_float4(0.f, 0.f, 0.f, 0.f);
        if (gr < n) v = *(const float4*)(in + (size_t)gr * K + k);
        if (BN) {
            float4 s4 = *(const float4*)(sc + k);
            float4 h4 = *(const float4*)(sh + k);
            v.x = eluf(v.x * s4.x + h4.x);
            v.y = eluf(v.y * s4.y + h4.y);
            v.z = eluf(v.z * s4.z + h4.z);
            v.w = eluf(v.w * s4.w + h4.w);
        }
        xs[k + 0][r] = v.x;
        xs[k + 1][r] = v.y;
        xs[k + 2][r] = v.z;
        xs[k + 3][r] = v.w;
    }
    __syncthreads();

    constexpr int CW = F / 16;       // cols per thread (8 or 4)
    int tx = t & 15;                 // col group
    int ty = t >> 4;                 // 0..31 -> 4 rows each
    float acc[4][CW];
    #pragma unroll
    for (int r = 0; r < 4; ++r)
        #pragma unroll
        for (int c = 0; c < CW; ++c) acc[r][c] = 0.f;

    for (int k = 0; k < K; ++k) {
        float4 xv = *(const float4*)&xs[k][ty * 4];
        float wv[CW];
        *(float4*)wv = *(const float4*)&ws[k][tx * CW];
        if (CW == 8) *(float4*)(wv + 4) = *(const float4*)&ws[k][tx * CW + 4];
        const float* xp = &xv.x;
        #pragma unroll
        for (int r = 0; r < 4; ++r)
            #pragma unroll
            for (int c = 0; c < CW; ++c)
                acc[r][c] = fmaf(xp[r], wv[c], acc[r][c]);
    }

    #pragma unroll
    for (int r = 0; r < 4; ++r) {
        int row = row0 + ty * 4 + r;
        if (row < n) {
            uint32_t p[CW / 2];
            #pragma unroll
            for (int c = 0; c < CW; c += 2)
                p[c / 2] = (uint32_t)f2bf(acc[r][c]) | ((uint32_t)f2bf(acc[r][c + 1]) << 16);
            if (CW == 8) {
                uint4 val = make_uint4(p[0], p[1], p[2], p[3]);
                *(uint4*)(h + (size_t)row * F + tx * CW) = val;
            } else {
                uint2 val = make_uint2(p[0], p[1]);
                *(uint2*)(h + (size_t)row * F + tx * CW) = val;
            }
        }
    }
}

// -------------------------------------------------------------------- AGG
// y[i] = sum_{e in CSR(i)} coef_e * h[src_e] + dis_i^2 * h[i] + b
// one wave per node; F=128: 2 cols/lane (uint32 = 2 bf16); F=64: 1 col/lane.
template <int F>
__global__ __launch_bounds__(256) void agg_kernel(
    const uint16_t* __restrict__ h,
    const int* __restrict__ row_start, const int* __restrict__ csr_src,
    const float* __restrict__ csr_coef, const float* __restrict__ dis,
    const float* __restrict__ bias, float* __restrict__ y, int n) {
    int wid = (int)((blockIdx.x * 256 + threadIdx.x) >> 6);
    int lane = threadIdx.x & 63;
    if (wid >= n) return;
    int s = row_start[wid], e = row_start[wid + 1];

    if (F == 128) {
        const uint32_t* hp = (const uint32_t*)h;
        float a0 = 0.f, a1 = 0.f;
        int i = s;
        for (; i + 2 <= e; i += 2) {
            int s0 = csr_src[i], s1 = csr_src[i + 1];
            float c0 = csr_coef[i], c1 = csr_coef[i + 1];
            uint32_t u0 = hp[(size_t)s0 * 64 + lane];
            uint32_t u1 = hp[(size_t)s1 * 64 + lane];
            a0 = fmaf(c0, bflo(u0), a0); a1 = fmaf(c0, bfhi(u0), a1);
            a0 = fmaf(c1, bflo(u1), a0); a1 = fmaf(c1, bfhi(u1), a1);
        }
        if (i < e) {
            int s0 = csr_src[i]; float c0 = csr_coef[i];
            uint32_t u0 = hp[(size_t)s0 * 64 + lane];
            a0 = fmaf(c0, bflo(u0), a0); a1 = fmaf(c0, bfhi(u0), a1);
        }
        float di = dis[wid], c2 = di * di;
        uint32_t u = hp[(size_t)wid * 64 + lane];
        a0 = fmaf(c2, bflo(u), a0) + bias[2 * lane];
        a1 = fmaf(c2, bfhi(u), a1) + bias[2 * lane + 1];
        *(float2*)(y + (size_t)wid * 128 + 2 * lane) = make_float2(a0, a1);
    } else {
        float a0 = 0.f;
        int i = s;
        for (; i + 2 <= e; i += 2) {
            int s0 = csr_src[i], s1 = csr_src[i + 1];
            float c0 = csr_coef[i], c1 = csr_coef[i + 1];
            uint32_t u0 = h[(size_t)s0 * 64 + lane];
            uint32_t u1 = h[(size_t)s1 * 64 + lane];
            a0 = fmaf(c0, bflo(u0), a0);
            a0 = fmaf(c1, bflo(u1), a0);
        }
        if (i < e) {
            int s0 = csr_src[i]; float c0 = csr_coef[i];
            a0 = fmaf(c0, bflo((uint32_t)h[(size_t)s0 * 64 + lane]), a0);
        }
        float di = dis[wid], c2 = di * di;
        a0 = fmaf(c2, bflo((uint32_t)h[(size_t)wid * 64 + lane]), a0) + bias[lane];
        y[(size_t)wid * 64 + lane] = a0;
    }
}

// ------------------------------------------------------------ BN statistics
template <int F>
__global__ __launch_bounds__(256) void colsum_kernel(
    const float* __restrict__ y, int n,
    float* __restrict__ sums, float* __restrict__ sumsq) {
    constexpr int CG = F / 4;         // float4 column groups
    constexpr int RP = 256 / CG;      // rows per block pass
    int t = threadIdx.x;
    int cg = t % CG, rt = t / CG;
    float4 s = make_float4(0.f, 0.f, 0.f, 0.f);
    float4 q = make_float4(0.f, 0.f, 0.f, 0.f);
    for (int row = blockIdx.x * RP + rt; row < n; row += gridDim.x * RP) {
        float4 v = *(const float4*)(y + (size_t)row * F + cg * 4);
        s.x += v.x; s.y += v.y; s.z += v.z; s.w += v.w;
        q.x += v.x * v.x; q.y += v.y * v.y; q.z += v.z * v.z; q.w += v.w * v.w;
    }
    __shared__ float4 rs[RP][CG], rq[RP][CG];
    rs[rt][cg] = s; rq[rt][cg] = q;
    __syncthreads();
    if (rt == 0) {
        #pragma unroll 4
        for (int j = 1; j < RP; ++j) {
            float4 o = rs[j][cg], p = rq[j][cg];
            s.x += o.x; s.y += o.y; s.z += o.z; s.w += o.w;
            q.x += p.x; q.y += p.y; q.z += p.z; q.w += p.w;
        }
        atomicAdd(&sums[cg * 4 + 0], s.x); atomicAdd(&sums[cg * 4 + 1], s.y);
        atomicAdd(&sums[cg * 4 + 2], s.z); atomicAdd(&sums[cg * 4 + 3], s.w);
        atomicAdd(&sumsq[cg * 4 + 0], q.x); atomicAdd(&sumsq[cg * 4 + 1], q.y);
        atomicAdd(&sumsq[cg * 4 + 2], q.z); atomicAdd(&sumsq[cg * 4 + 3], q.w);
    }
}

template <int F>
__global__ void finalize_kernel(const float* __restrict__ sums,
                                const float* __restrict__ sumsq,
                                const float* __restrict__ g, const float* __restrict__ be,
                                float* __restrict__ sc, float* __restrict__ sh, float n) {
    int c = threadIdx.x;
    if (c < F) {
        float m = sums[c] / n;
        float v = sumsq[c] / n - m * m;           // biased variance
        float r = rsqrtf(v + 1e-5f);
        float scale = r * g[c];
        sc[c] = scale;
        sh[c] = be[c] - m * scale;
    }
}

// ----------------------------------------------------------- final BN+ELU
__global__ __launch_bounds__(256) void out_kernel(
    const float* __restrict__ y, const float* __restrict__ sc,
    const float* __restrict__ sh, float* __restrict__ out, int total4) {
    int idx = blockIdx.x * 256 + threadIdx.x;
    if (idx >= total4) return;
    int cg = (idx & 15) * 4;   // 64 cols = 16 float4 per row
    float4 v = *(const float4*)(y + (size_t)idx * 4);
    float4 s4 = *(const float4*)(sc + cg);
    float4 h4 = *(const float4*)(sh + cg);
    v.x = eluf(v.x * s4.x + h4.x);
    v.y = eluf(v.y * s4.y + h4.y);
    v.z = eluf(v.z * s4.z + h4.z);
    v.w = eluf(v.w * s4.w + h4.w);
    *(float4*)(out + (size_t)idx * 4) = v;
}

// ---------------------------------------------------------------------------
extern "C" void kernel_launch(void* const* d_in, const int* in_sizes, int n_in,
                              void* d_out, int out_size, void* d_ws, size_t ws_size,
                              hipStream_t stream) {
    const float* x    = (const float*)d_in[0];
    const int*   edge = (const int*)d_in[1];
    const float* W0 = (const float*)d_in[2];
    const float* b0 = (const float*)d_in[3];
    const float* g0 = (const float*)d_in[4];
    const float* be0 = (const float*)d_in[5];
    const float* W1 = (const float*)d_in[6];
    const float* b1 = (const float*)d_in[7];
    const float* g1 = (const float*)d_in[8];
    const float* be1 = (const float*)d_in[9];
    const float* W2 = (const float*)d_in[10];
    const float* b2 = (const float*)d_in[11];
    const float* g2 = (const float*)d_in[12];
    const float* be2 = (const float*)d_in[13];

    const int n = in_sizes[0] / 128;     // 50000
    const int E = in_sizes[1] / 2;       // 1600000
    const int* esrc = edge;
    const int* edst = edge + E;

    // workspace carve (256B aligned)
    char* w = (char*)d_ws;
    auto carve = [&](size_t bytes) -> void* {
        void* p = (void*)w;
        w += (bytes + 255) & ~(size_t)255;
        return p;
    };
    float*    y        = (float*)carve((size_t)n * 128 * 4);
    uint16_t* h        = (uint16_t*)carve((size_t)n * 128 * 2);
    int*      csr_src  = (int*)carve((size_t)E * 4);
    float*    csr_coef = (float*)carve((size_t)E * 4);
    int*      row_start= (int*)carve((size_t)(n + 1) * 4);
    int*      deg      = (int*)carve((size_t)n * 4);
    int*      cursor   = (int*)carve((size_t)n * 4);
    float*    dis      = (float*)carve((size_t)n * 4);
    float*    sums     = (float*)carve(128 * 4);
    float*    sumsq    = (float*)carve(128 * 4);
    float*    sc       = (float*)carve(128 * 4);
    float*    sh       = (float*)carve(128 * 4);

    int gE = (E + 255) / 256;
    int gN = (n + 255) / 256;

    // ---- CSR build
    hipMemsetAsync(deg, 0, (size_t)n * 4, stream);
    hipMemsetAsync(cursor, 0, (size_t)n * 4, stream);
    count_kernel<<<gE, 256, 0, stream>>>(edst, deg, E);
    dis_kernel<<<gN, 256, 0, stream>>>(deg, dis, n);
    scan_kernel<<<1, 1024, 0, stream>>>(deg, row_start, n);
    scatter_kernel<<<gE, 256, 0, stream>>>(esrc, edst, row_start, cursor, dis,
                                           csr_src, csr_coef, E);

    int gGemm = (n + 127) / 128;
    int gAgg  = (n + 3) / 4;

    // ---- layer 0 (in = x, no BN on input)
    gemm_kernel<128, false><<<gGemm, 512, 0, stream>>>(x, W0, nullptr, nullptr, h, n);
    agg_kernel<128><<<gAgg, 256, 0, stream>>>(h, row_start, csr_src, csr_coef, dis, b0, y, n);
    hipMemsetAsync(sums, 0, 128 * 4, stream);
    hipMemsetAsync(sumsq, 0, 128 * 4, stream);
    colsum_kernel<128><<<256, 256, 0, stream>>>(y, n, sums, sumsq);
    finalize_kernel<128><<<1, 128, 0, stream>>>(sums, sumsq, g0, be0, sc, sh, (float)n);

    // ---- layer 1 (in = y with BN0+ELU fused)
    gemm_kernel<128, true><<<gGemm, 512, 0, stream>>>(y, W1, sc, sh, h, n);
    agg_kernel<128><<<gAgg, 256, 0, stream>>>(h, row_start, csr_src, csr_coef, dis, b1, y, n);
    hipMemsetAsync(sums, 0, 128 * 4, stream);
    hipMemsetAsync(sumsq, 0, 128 * 4, stream);
    colsum_kernel<128><<<256, 256, 0, stream>>>(y, n, sums, sumsq);
    finalize_kernel<128><<<1, 128, 0, stream>>>(sums, sumsq, g1, be1, sc, sh, (float)n);

    // ---- layer 2 (in = y with BN1+ELU fused, F=64)
    gemm_kernel<64, true><<<gGemm, 512, 0, stream>>>(y, W2, sc, sh, h, n);
    agg_kernel<64><<<gAgg, 256, 0, stream>>>(h, row_start, csr_src, csr_coef, dis, b2, y, n);
    hipMemsetAsync(sums, 0, 64 * 4, stream);
    hipMemsetAsync(sumsq, 0, 64 * 4, stream);
    colsum_kernel<64><<<256, 256, 0, stream>>>(y, n, sums, sumsq);
    finalize_kernel<64><<<1, 64, 0, stream>>>(sums, sumsq, g2, be2, sc, sh, (float)n);

    // ---- final BN2 + ELU -> out
    int total4 = n * 16;   // n*64/4
    out_kernel<<<(total4 + 255) / 256, 256, 0, stream>>>(y, sc, sh, (float*)d_out, total4);
}

// Round 2
// 653.187 us; speedup vs baseline: 1.2259x; 1.2259x over previous
//
#include <hip/hip_runtime.h>
#include <hip/hip_bf16.h>
#include <stdint.h>

// ---------------------------------------------------------------------------
// GNNEncoder: 3 x (GCNConv -> BatchNorm1d(train) -> ELU)
// N=50000 nodes, E=1.6M edges, dims 128->128->128->64
//
// R2: scatter de-amplification.
//  - count_rank fuses rank[e] = atomicAdd(deg[dst],1)  (no atomic in scatter)
//  - scatter writes ONLY csr_src (4B/edge); coef computed on the fly in AGG
//  - scan kernel also produces dis
//  - AGG unrolled x4 with independent gathers in flight
// ---------------------------------------------------------------------------

static __device__ __forceinline__ float bflo(uint32_t u) {
    union { uint32_t u; float f; } x; x.u = u << 16; return x.f;
}
static __device__ __forceinline__ float bfhi(uint32_t u) {
    union { uint32_t u; float f; } x; x.u = u & 0xffff0000u; return x.f;
}
static __device__ __forceinline__ uint16_t f2bf(float f) {
    union { float f; uint32_t u; } x; x.f = f;
    uint32_t r = x.u + 0x7fffu + ((x.u >> 16) & 1u);   // RNE
    return (uint16_t)(r >> 16);
}
static __device__ __forceinline__ float eluf(float v) {
    return v > 0.f ? v : expm1f(v);
}

// ---------------------------------------------------------------- CSR build
__global__ __launch_bounds__(256) void count_rank_kernel(
    const int* __restrict__ dst, int* __restrict__ deg,
    int* __restrict__ rank, int E) {
    int e = blockIdx.x * 256 + threadIdx.x;
    if (e < E) rank[e] = atomicAdd(&deg[dst[e]], 1);
}

__global__ __launch_bounds__(1024) void scan_kernel(const int* __restrict__ deg,
                                                    int* __restrict__ row_start,
                                                    float* __restrict__ dis, int n) {
    __shared__ int wtot[16];
    int t = threadIdx.x, lane = t & 63, w = t >> 6;
    int carry = 0;
    for (int base = 0; base < n; base += 1024) {
        int i = base + t;
        int v = (i < n) ? deg[i] : 0;
        int x = v;
        #pragma unroll
        for (int off = 1; off < 64; off <<= 1) {
            int m = __shfl_up(x, off);
            if (lane >= off) x += m;
        }
        if (lane == 63) wtot[w] = x;
        __syncthreads();
        int woff = 0, tot = 0;
        #pragma unroll
        for (int j = 0; j < 16; ++j) {
            int wv = wtot[j];
            tot += wv;
            if (j < w) woff += wv;
        }
        if (i < n) {
            row_start[i] = carry + woff + (x - v);  // exclusive
            dis[i] = rsqrtf(1.0f + (float)v);
        }
        carry += tot;
        __syncthreads();
    }
    if (t == 0) row_start[n] = carry;
}

__global__ __launch_bounds__(256) void scatter_kernel(
    const int* __restrict__ src, const int* __restrict__ dst,
    const int* __restrict__ rank, const int* __restrict__ row_start,
    int* __restrict__ csr_src, int E) {
    int e = blockIdx.x * 256 + threadIdx.x;
    if (e >= E) return;
    int d = dst[e];
    csr_src[row_start[d] + rank[e]] = src[e];
}

// ------------------------------------------------------------------- GEMM
// h[n][F] (bf16) = act(in)[n][128] @ W[128][F];  act = BN+ELU (fused) or id.
template <int F, bool BN>
__global__ __launch_bounds__(512) void gemm_kernel(
    const float* __restrict__ in, const float* __restrict__ W,
    const float* __restrict__ sc, const float* __restrict__ sh,
    uint16_t* __restrict__ h, int n) {
    constexpr int K = 128;
    constexpr int BM = 128;
    __shared__ float xs[K][BM + 4];   // transposed: xs[k][r]
    __shared__ float ws[K][F];
    int t = threadIdx.x;
    int row0 = blockIdx.x * BM;

    for (int i = t * 4; i < K * F; i += 512 * 4) {
        *(float4*)((float*)ws + i) = *(const float4*)(W + i);
    }
    for (int idx = t; idx < BM * K / 4; idx += 512) {
        int r = idx >> 5;
        int k = (idx & 31) << 2;
        int gr = row0 + r;
        float4 v = make_float4(0.f, 0.f, 0.f, 0.f);
        if (gr < n) v = *(const float4*)(in + (size_t)gr * K + k);
        if (BN) {
            float4 s4 = *(const float4*)(sc + k);
            float4 h4 = *(const float4*)(sh + k);
            v.x = eluf(v.x * s4.x + h4.x);
            v.y = eluf(v.y * s4.y + h4.y);
            v.z = eluf(v.z * s4.z + h4.z);
            v.w = eluf(v.w * s4.w + h4.w);
        }
        xs[k + 0][r] = v.x;
        xs[k + 1][r] = v.y;
        xs[k + 2][r] = v.z;
        xs[k + 3][r] = v.w;
    }
    __syncthreads();

    constexpr int CW = F / 16;
    int tx = t & 15;
    int ty = t >> 4;
    float acc[4][CW];
    #pragma unroll
    for (int r = 0; r < 4; ++r)
        #pragma unroll
        for (int c = 0; c < CW; ++c) acc[r][c] = 0.f;

    for (int k = 0; k < K; ++k) {
        float4 xv = *(const float4*)&xs[k][ty * 4];
        float wv[CW];
        *(float4*)wv = *(const float4*)&ws[k][tx * CW];
        if (CW == 8) *(float4*)(wv + 4) = *(const float4*)&ws[k][tx * CW + 4];
        const float* xp = &xv.x;
        #pragma unroll
        for (int r = 0; r < 4; ++r)
            #pragma unroll
            for (int c = 0; c < CW; ++c)
                acc[r][c] = fmaf(xp[r], wv[c], acc[r][c]);
    }

    #pragma unroll
    for (int r = 0; r < 4; ++r) {
        int row = row0 + ty * 4 + r;
        if (row < n) {
            uint32_t p[CW / 2];
            #pragma unroll
            for (int c = 0; c < CW; c += 2)
                p[c / 2] = (uint32_t)f2bf(acc[r][c]) | ((uint32_t)f2bf(acc[r][c + 1]) << 16);
            if (CW == 8) {
                uint4 val = make_uint4(p[0], p[1], p[2], p[3]);
                *(uint4*)(h + (size_t)row * F + tx * CW) = val;
            } else {
                uint2 val = make_uint2(p[0], p[1]);
                *(uint2*)(h + (size_t)row * F + tx * CW) = val;
            }
        }
    }
}

// -------------------------------------------------------------------- AGG
// y[i] = sum_{e in CSR(i)} dis[src]*dis[i] * h[src] + dis_i^2 * h[i] + b
// one wave per node; coef computed on the fly (scalar loads from dis).
template <int F>
__global__ __launch_bounds__(256) void agg_kernel(
    const uint16_t* __restrict__ h,
    const int* __restrict__ row_start, const int* __restrict__ csr_src,
    const float* __restrict__ dis,
    const float* __restrict__ bias, float* __restrict__ y, int n) {
    int wid = (int)((blockIdx.x * 256 + threadIdx.x) >> 6);
    int lane = threadIdx.x & 63;
    if (wid >= n) return;
    int s = row_start[wid], e = row_start[wid + 1];
    float dd = dis[wid];

    if (F == 128) {
        const uint32_t* hp = (const uint32_t*)h;
        float a0 = 0.f, a1 = 0.f;
        int i = s;
        for (; i + 4 <= e; i += 4) {
            int s0 = csr_src[i], s1 = csr_src[i + 1];
            int s2 = csr_src[i + 2], s3 = csr_src[i + 3];
            uint32_t u0 = hp[(size_t)s0 * 64 + lane];
            uint32_t u1 = hp[(size_t)s1 * 64 + lane];
            uint32_t u2 = hp[(size_t)s2 * 64 + lane];
            uint32_t u3 = hp[(size_t)s3 * 64 + lane];
            float c0 = dis[s0] * dd, c1 = dis[s1] * dd;
            float c2 = dis[s2] * dd, c3 = dis[s3] * dd;
            a0 = fmaf(c0, bflo(u0), a0); a1 = fmaf(c0, bfhi(u0), a1);
            a0 = fmaf(c1, bflo(u1), a0); a1 = fmaf(c1, bfhi(u1), a1);
            a0 = fmaf(c2, bflo(u2), a0); a1 = fmaf(c2, bfhi(u2), a1);
            a0 = fmaf(c3, bflo(u3), a0); a1 = fmaf(c3, bfhi(u3), a1);
        }
        for (; i < e; ++i) {
            int s0 = csr_src[i];
            float c0 = dis[s0] * dd;
            uint32_t u0 = hp[(size_t)s0 * 64 + lane];
            a0 = fmaf(c0, bflo(u0), a0); a1 = fmaf(c0, bfhi(u0), a1);
        }
        float c2 = dd * dd;
        uint32_t u = hp[(size_t)wid * 64 + lane];
        a0 = fmaf(c2, bflo(u), a0) + bias[2 * lane];
        a1 = fmaf(c2, bfhi(u), a1) + bias[2 * lane + 1];
        *(float2*)(y + (size_t)wid * 128 + 2 * lane) = make_float2(a0, a1);
    } else {
        float a0 = 0.f;
        int i = s;
        for (; i + 4 <= e; i += 4) {
            int s0 = csr_src[i], s1 = csr_src[i + 1];
            int s2 = csr_src[i + 2], s3 = csr_src[i + 3];
            uint32_t u0 = h[(size_t)s0 * 64 + lane];
            uint32_t u1 = h[(size_t)s1 * 64 + lane];
            uint32_t u2 = h[(size_t)s2 * 64 + lane];
            uint32_t u3 = h[(size_t)s3 * 64 + lane];
            float c0 = dis[s0] * dd, c1 = dis[s1] * dd;
            float c2 = dis[s2] * dd, c3 = dis[s3] * dd;
            a0 = fmaf(c0, bflo(u0), a0);
            a0 = fmaf(c1, bflo(u1), a0);
            a0 = fmaf(c2, bflo(u2), a0);
            a0 = fmaf(c3, bflo(u3), a0);
        }
        for (; i < e; ++i) {
            int s0 = csr_src[i];
            float c0 = dis[s0] * dd;
            a0 = fmaf(c0, bflo((uint32_t)h[(size_t)s0 * 64 + lane]), a0);
        }
        float c2 = dd * dd;
        a0 = fmaf(c2, bflo((uint32_t)h[(size_t)wid * 64 + lane]), a0) + bias[lane];
        y[(size_t)wid * 64 + lane] = a0;
    }
}

// ------------------------------------------------------------ BN statistics
template <int F>
__global__ __launch_bounds__(256) void colsum_kernel(
    const float* __restrict__ y, int n,
    float* __restrict__ sums, float* __restrict__ sumsq) {
    constexpr int CG = F / 4;
    constexpr int RP = 256 / CG;
    int t = threadIdx.x;
    int cg = t % CG, rt = t / CG;
    float4 s = make_float4(0.f, 0.f, 0.f, 0.f);
    float4 q = make_float4(0.f, 0.f, 0.f, 0.f);
    for (int row = blockIdx.x * RP + rt; row < n; row += gridDim.x * RP) {
        float4 v = *(const float4*)(y + (size_t)row * F + cg * 4);
        s.x += v.x; s.y += v.y; s.z += v.z; s.w += v.w;
        q.x += v.x * v.x; q.y += v.y * v.y; q.z += v.z * v.z; q.w += v.w * v.w;
    }
    __shared__ float4 rs[RP][CG], rq[RP][CG];
    rs[rt][cg] = s; rq[rt][cg] = q;
    __syncthreads();
    if (rt == 0) {
        #pragma unroll 4
        for (int j = 1; j < RP; ++j) {
            float4 o = rs[j][cg], p = rq[j][cg];
            s.x += o.x; s.y += o.y; s.z += o.z; s.w += o.w;
            q.x += p.x; q.y += p.y; q.z += p.z; q.w += p.w;
        }
        atomicAdd(&sums[cg * 4 + 0], s.x); atomicAdd(&sums[cg * 4 + 1], s.y);
        atomicAdd(&sums[cg * 4 + 2], s.z); atomicAdd(&sums[cg * 4 + 3], s.w);
        atomicAdd(&sumsq[cg * 4 + 0], q.x); atomicAdd(&sumsq[cg * 4 + 1], q.y);
        atomicAdd(&sumsq[cg * 4 + 2], q.z); atomicAdd(&sumsq[cg * 4 + 3], q.w);
    }
}

template <int F>
__global__ void finalize_kernel(const float* __restrict__ sums,
                                const float* __restrict__ sumsq,
                                const float* __restrict__ g, const float* __restrict__ be,
                                float* __restrict__ sc, float* __restrict__ sh, float n) {
    int c = threadIdx.x;
    if (c < F) {
        float m = sums[c] / n;
        float v = sumsq[c] / n - m * m;           // biased variance
        float r = rsqrtf(v + 1e-5f);
        float scale = r * g[c];
        sc[c] = scale;
        sh[c] = be[c] - m * scale;
    }
}

// ----------------------------------------------------------- final BN+ELU
__global__ __launch_bounds__(256) void out_kernel(
    const float* __restrict__ y, const float* __restrict__ sc,
    const float* __restrict__ sh, float* __restrict__ out, int total4) {
    int idx = blockIdx.x * 256 + threadIdx.x;
    if (idx >= total4) return;
    int cg = (idx & 15) * 4;
    float4 v = *(const float4*)(y + (size_t)idx * 4);
    float4 s4 = *(const float4*)(sc + cg);
    float4 h4 = *(const float4*)(sh + cg);
    v.x = eluf(v.x * s4.x + h4.x);
    v.y = eluf(v.y * s4.y + h4.y);
    v.z = eluf(v.z * s4.z + h4.z);
    v.w = eluf(v.w * s4.w + h4.w);
    *(float4*)(out + (size_t)idx * 4) = v;
}

// ---------------------------------------------------------------------------
extern "C" void kernel_launch(void* const* d_in, const int* in_sizes, int n_in,
                              void* d_out, int out_size, void* d_ws, size_t ws_size,
                              hipStream_t stream) {
    const float* x    = (const float*)d_in[0];
    const int*   edge = (const int*)d_in[1];
    const float* W0 = (const float*)d_in[2];
    const float* b0 = (const float*)d_in[3];
    const float* g0 = (const float*)d_in[4];
    const float* be0 = (const float*)d_in[5];
    const float* W1 = (const float*)d_in[6];
    const float* b1 = (const float*)d_in[7];
    const float* g1 = (const float*)d_in[8];
    const float* be1 = (const float*)d_in[9];
    const float* W2 = (const float*)d_in[10];
    const float* b2 = (const float*)d_in[11];
    const float* g2 = (const float*)d_in[12];
    const float* be2 = (const float*)d_in[13];

    const int n = in_sizes[0] / 128;     // 50000
    const int E = in_sizes[1] / 2;       // 1600000
    const int* esrc = edge;
    const int* edst = edge + E;

    char* w = (char*)d_ws;
    auto carve = [&](size_t bytes) -> void* {
        void* p = (void*)w;
        w += (bytes + 255) & ~(size_t)255;
        return p;
    };
    float*    y        = (float*)carve((size_t)n * 128 * 4);
    uint16_t* h        = (uint16_t*)carve((size_t)n * 128 * 2);
    int*      csr_src  = (int*)carve((size_t)E * 4);
    int*      rank     = (int*)carve((size_t)E * 4);
    int*      row_start= (int*)carve((size_t)(n + 1) * 4);
    int*      deg      = (int*)carve((size_t)n * 4);
    float*    dis      = (float*)carve((size_t)n * 4);
    float*    sums     = (float*)carve(128 * 4);
    float*    sumsq    = (float*)carve(128 * 4);
    float*    sc       = (float*)carve(128 * 4);
    float*    sh       = (float*)carve(128 * 4);

    int gE = (E + 255) / 256;

    // ---- CSR build
    hipMemsetAsync(deg, 0, (size_t)n * 4, stream);
    count_rank_kernel<<<gE, 256, 0, stream>>>(edst, deg, rank, E);
    scan_kernel<<<1, 1024, 0, stream>>>(deg, row_start, dis, n);
    scatter_kernel<<<gE, 256, 0, stream>>>(esrc, edst, rank, row_start, csr_src, E);

    int gGemm = (n + 127) / 128;
    int gAgg  = (n + 3) / 4;

    // ---- layer 0 (in = x, no BN on input)
    gemm_kernel<128, false><<<gGemm, 512, 0, stream>>>(x, W0, nullptr, nullptr, h, n);
    agg_kernel<128><<<gAgg, 256, 0, stream>>>(h, row_start, csr_src, dis, b0, y, n);
    hipMemsetAsync(sums, 0, 128 * 4, stream);
    hipMemsetAsync(sumsq, 0, 128 * 4, stream);
    colsum_kernel<128><<<256, 256, 0, stream>>>(y, n, sums, sumsq);
    finalize_kernel<128><<<1, 128, 0, stream>>>(sums, sumsq, g0, be0, sc, sh, (float)n);

    // ---- layer 1
    gemm_kernel<128, true><<<gGemm, 512, 0, stream>>>(y, W1, sc, sh, h, n);
    agg_kernel<128><<<gAgg, 256, 0, stream>>>(h, row_start, csr_src, dis, b1, y, n);
    hipMemsetAsync(sums, 0, 128 * 4, stream);
    hipMemsetAsync(sumsq, 0, 128 * 4, stream);
    colsum_kernel<128><<<256, 256, 0, stream>>>(y, n, sums, sumsq);
    finalize_kernel<128><<<1, 128, 0, stream>>>(sums, sumsq, g1, be1, sc, sh, (float)n);

    // ---- layer 2 (F=64)
    gemm_kernel<64, true><<<gGemm, 512, 0, stream>>>(y, W2, sc, sh, h, n);
    agg_kernel<64><<<gAgg, 256, 0, stream>>>(h, row_start, csr_src, dis, b2, y, n);
    hipMemsetAsync(sums, 0, 64 * 4, stream);
    hipMemsetAsync(sumsq, 0, 64 * 4, stream);
    colsum_kernel<64><<<256, 256, 0, stream>>>(y, n, sums, sumsq);
    finalize_kernel<64><<<1, 64, 0, stream>>>(sums, sumsq, g2, be2, sc, sh, (float)n);

    // ---- final BN2 + ELU -> out
    int total4 = n * 16;
    out_kernel<<<(total4 + 255) / 256, 256, 0, stream>>>(y, sc, sh, (float*)d_out, total4);
}